// Round 12
// baseline (557.996 us; speedup 1.0000x reference)
//
#include <hip/hip_runtime.h>
#include <math.h>

#define BATCH   512
#define IN_DIM  256
#define OUT_DIM 256
#define NDEG    6     // degree+1

#define OT     8     // o per block
#define NSEG   32    // i-segments per block (tid>>3)
#define ISEG   8     // i's per segment
#define NB     8     // b per block (register accumulators)
#define REPEAT 12    // probe amplification (each probe > 41us -> in top-5)

// ---------------------------------------------------------------------------
// Real path = R10 exact (best known, 23.3us): LSE -> poly in t=e^x, lane-
// ordered coef layout, 2^-18 prescale (4-i log batching), op_sel packed
// Horner, NB=8, grid (32,64).
// R12 adds 5 DISTINCTLY-NAMED ablation probes (REPEAT=12) so the counter
// table's Kernel_Name column identifies each: full / nolog / nolds / novmem
// / skel. Decision rules pre-committed in the journal.
// ---------------------------------------------------------------------------

typedef float v2f __attribute__((ext_vector_type(2)));

__device__ __forceinline__ v2f pk_fma_blo(v2f a, v2f t, v2f c) {
    v2f d;
    asm("v_pk_fma_f32 %0, %1, %2, %3 op_sel:[0,0,0] op_sel_hi:[1,0,1]"
        : "=v"(d) : "v"(a), "v"(t), "v"(c));
    return d;
}
__device__ __forceinline__ v2f pk_fma_bhi(v2f a, v2f t, v2f c) {
    v2f d;
    asm("v_pk_fma_f32 %0, %1, %2, %3 op_sel:[0,1,0] op_sel_hi:[1,1,1]"
        : "=v"(d) : "v"(a), "v"(t), "v"(c));
    return d;
}
__device__ __forceinline__ v2f pk_mul(v2f a, v2f b) {
    v2f d;
    asm("v_pk_mul_f32 %0, %1, %2" : "=v"(d) : "v"(a), "v"(b));
    return d;
}

#define PRESCALE 12.476649250079015f   // 18 * ln2

__global__ void prep_pack(const float* __restrict__ wp,
                          const float* __restrict__ wq,
                          float4* __restrict__ pk2) {
    int j = blockIdx.x * blockDim.x + threadIdx.x;   // j = i*OUT_DIM + o
    if (j >= IN_DIM * OUT_DIM) return;
    const int i = j >> 8, o = j & 255;
    const int seg_blk = i >> 6;
    const int seg     = (i >> 3) & 7;
    const int ii      = i & 7;
    const int o_blk   = o >> 3;
    const int o_l     = o & 7;
    const size_t base =
        ((size_t)(o_blk * 4 + seg_blk) * 24) * 64 + seg * 8 + o_l;

    const float2* wp2 = (const float2*)wp;
    const float2* wq2 = (const float2*)wq;
    float2 p0 = wp2[j * 3], p1 = wp2[j * 3 + 1], p2 = wp2[j * 3 + 2];
    float2 q0 = wq2[j * 3], q1 = wq2[j * 3 + 1], q2 = wq2[j * 3 + 2];
    pk2[base + (ii * 3 + 0) * 64] =
        make_float4(__expf(p0.x - PRESCALE), __expf(q0.x - PRESCALE),
                    __expf(p0.y - PRESCALE), __expf(q0.y - PRESCALE));
    pk2[base + (ii * 3 + 1) * 64] =
        make_float4(__expf(p1.x - PRESCALE), __expf(q1.x - PRESCALE),
                    __expf(p1.y - PRESCALE), __expf(q1.y - PRESCALE));
    pk2[base + (ii * 3 + 2) * 64] =
        make_float4(__expf(p2.x - PRESCALE), __expf(q2.x - PRESCALE),
                    __expf(p2.y - PRESCALE), __expf(q2.y - PRESCALE));
}

__device__ __forceinline__ v2f horner_lo(float4 c0, float4 c1, float4 c2, v2f tp) {
    const v2f C0 = {c0.x, c0.y}, C1 = {c0.z, c0.w};
    const v2f C2 = {c1.x, c1.y}, C3 = {c1.z, c1.w};
    const v2f C4 = {c2.x, c2.y}, C5 = {c2.z, c2.w};
    v2f r = pk_fma_blo(C5, tp, C4);
    r = pk_fma_blo(r, tp, C3);
    r = pk_fma_blo(r, tp, C2);
    r = pk_fma_blo(r, tp, C1);
    r = pk_fma_blo(r, tp, C0);
    return r;
}
__device__ __forceinline__ v2f horner_hi(float4 c0, float4 c1, float4 c2, v2f tp) {
    const v2f C0 = {c0.x, c0.y}, C1 = {c0.z, c0.w};
    const v2f C2 = {c1.x, c1.y}, C3 = {c1.z, c1.w};
    const v2f C4 = {c2.x, c2.y}, C5 = {c2.z, c2.w};
    v2f r = pk_fma_bhi(C5, tp, C4);
    r = pk_fma_bhi(r, tp, C3);
    r = pk_fma_bhi(r, tp, C2);
    r = pk_fma_bhi(r, tp, C1);
    r = pk_fma_bhi(r, tp, C0);
    return r;
}

// ---- REAL kernel (R10 exact) ----
__launch_bounds__(256, 4)
__global__ void tropical_main(const float* __restrict__ x,
                              const float4* __restrict__ pk2,
                              float* __restrict__ out) {
    __shared__ float lds[NSEG * (NB * OT + 1)];   // 2080 floats

    const int tid = threadIdx.x;
    const int o_l = tid & (OT - 1);
    const int b0  = blockIdx.y * NB;

    {
        const int r = tid >> 5;
        const int c = (tid & 31) * 8;
        const float* xr = x + (size_t)(b0 + r) * IN_DIM + c;
        const float4 v0 = *(const float4*)(xr);
        const float4 v1 = *(const float4*)(xr + 4);
        float4 w0, w1;
        w0.x = __expf(v0.x); w0.y = __expf(v0.y);
        w0.z = __expf(v0.z); w0.w = __expf(v0.w);
        w1.x = __expf(v1.x); w1.y = __expf(v1.y);
        w1.z = __expf(v1.z); w1.w = __expf(v1.w);
        *(float4*)&lds[r * IN_DIM + c]     = w0;
        *(float4*)&lds[r * IN_DIM + c + 4] = w1;
    }
    __syncthreads();

    float acc[NB];
#pragma unroll
    for (int b = 0; b < NB; ++b) acc[b] = 0.f;

    const int lane = tid & 63;
    const int wv   = tid >> 6;
    const float4* __restrict__ cb =
        pk2 + ((size_t)(blockIdx.x * 4 + wv) * 24) * 64 + lane;

    const int i0 = (tid >> 3) * ISEG;
    const float* __restrict__ tb = lds + i0;

#pragma unroll
    for (int g = 0; g < 2; ++g) {
        float4 C[12];
#pragma unroll
        for (int k = 0; k < 12; ++k)
            C[k] = cb[(g * 12 + k) * 64];

#pragma unroll
        for (int b = 0; b < NB; ++b) {
            const float4 tv = *(const float4*)(tb + b * IN_DIM + g * 4);
            const v2f txy = {tv.x, tv.y};
            const v2f tzw = {tv.z, tv.w};
            const v2f PQ0 = horner_lo(C[0], C[1],  C[2],  txy);
            const v2f PQ1 = horner_hi(C[3], C[4],  C[5],  txy);
            const v2f PQ2 = horner_lo(C[6], C[7],  C[8],  tzw);
            const v2f PQ3 = horner_hi(C[9], C[10], C[11], tzw);
            const v2f m = pk_mul(pk_mul(PQ0, PQ1), pk_mul(PQ2, PQ3));
            acc[b] += __log2f(m.x) - __log2f(m.y);
        }
    }

    __syncthreads();
    const int seg = tid >> 3;
#pragma unroll
    for (int b = 0; b < NB; ++b)
        lds[seg * (NB * OT + 1) + b * OT + o_l] = acc[b];
    __syncthreads();

    if (tid < NB * OT) {
        const int br = tid >> 3, orr = tid & (OT - 1);
        float s = 0.f;
#pragma unroll
        for (int g = 0; g < NSEG; ++g)
            s += lds[g * (NB * OT + 1) + br * OT + orr];
        out[(size_t)(b0 + br) * OUT_DIM + blockIdx.x * OT + orr] =
            s * 0.6931471805599453f;
    }
}

// ---- ABLATION PROBE BODY (R10 body + REPEAT, component toggles) ----
template<int NOLOG, int NOLDS, int NOVMEM, int SKEL>
__device__ __forceinline__ void probe_body(const float* __restrict__ x,
                                           const float4* __restrict__ pk2,
                                           float* __restrict__ sink) {
    __shared__ float lds[NSEG * (NB * OT + 1)];
    const int tid = threadIdx.x;
    const int b0  = blockIdx.y * NB;

    {   // staging (kept alive in all modes via dummy read below)
        const int r = tid >> 5;
        const int c = (tid & 31) * 8;
        const float* xr = x + (size_t)(b0 + r) * IN_DIM + c;
        const float4 v0 = *(const float4*)(xr);
        const float4 v1 = *(const float4*)(xr + 4);
        float4 w0, w1;
        w0.x = __expf(v0.x); w0.y = __expf(v0.y);
        w0.z = __expf(v0.z); w0.w = __expf(v0.w);
        w1.x = __expf(v1.x); w1.y = __expf(v1.y);
        w1.z = __expf(v1.z); w1.w = __expf(v1.w);
        *(float4*)&lds[r * IN_DIM + c]     = w0;
        *(float4*)&lds[r * IN_DIM + c + 4] = w1;
    }
    __syncthreads();
    {   // keep staging live even when NOLDS skips t-reads
        float dummy = lds[tid];
        asm volatile("" :: "v"(dummy));
    }

    float acc[NB];
#pragma unroll
    for (int b = 0; b < NB; ++b) acc[b] = 0.f;

    const int lane = tid & 63;
    const int wv   = tid >> 6;
    const float4* __restrict__ cb =
        pk2 + ((size_t)(blockIdx.x * 4 + wv) * 24) * 64 + lane;
    const int i0 = (tid >> 3) * ISEG;
    const float* __restrict__ tb = lds + i0;

    float4 Ch[12];
    if constexpr (NOVMEM) {
#pragma unroll
        for (int k = 0; k < 12; ++k) Ch[k] = cb[k * 64];
    }

#pragma unroll 1
    for (int r = 0; r < REPEAT; ++r) {
        int rz = r;
        asm volatile("" : "+v"(rz));       // opaque copy of r
        const int z = rz - r;              // runtime 0, opaque at compile
        const float4* cbr = cb + z;
        const float*  tbr = tb + z;

#pragma unroll
        for (int g = 0; g < 2; ++g) {
            float4 C[12];
            if constexpr (NOVMEM) {
#pragma unroll
                for (int k = 0; k < 12; ++k) C[k] = Ch[k];   // copy-propagated
            } else {
#pragma unroll
                for (int k = 0; k < 12; ++k) C[k] = cbr[(g * 12 + k) * 64];
            }
            if constexpr (SKEL) {   // keep every loaded lane live
#pragma unroll
                for (int k = 0; k < 12; ++k)
                    asm volatile("" :: "v"(C[k].x), "v"(C[k].y),
                                       "v"(C[k].z), "v"(C[k].w));
            }

#pragma unroll
            for (int b = 0; b < NB; ++b) {
                float4 tv;
                if constexpr (NOLDS) {
                    const float base =
                        1.0f + 0.01f * (float)((((b << 2) + g) + rz) & 31);
                    tv = make_float4(base, base + 0.01f, base + 0.02f,
                                     base + 0.03f);
                } else {
                    tv = *(const float4*)(tbr + b * IN_DIM + g * 4);
                }
                if constexpr (SKEL) {
                    acc[b] += fmaf(C[0].x, tv.x, C[11].w * tv.w);
                } else {
                    const v2f txy = {tv.x, tv.y};
                    const v2f tzw = {tv.z, tv.w};
                    const v2f PQ0 = horner_lo(C[0], C[1],  C[2],  txy);
                    const v2f PQ1 = horner_hi(C[3], C[4],  C[5],  txy);
                    const v2f PQ2 = horner_lo(C[6], C[7],  C[8],  tzw);
                    const v2f PQ3 = horner_hi(C[9], C[10], C[11], tzw);
                    const v2f m = pk_mul(pk_mul(PQ0, PQ1), pk_mul(PQ2, PQ3));
                    if constexpr (NOLOG) {
                        acc[b] += m.x - m.y;
                    } else {
                        acc[b] += __log2f(m.x) - __log2f(m.y);
                    }
                }
            }
        }
    }

    float s = 0.f;
#pragma unroll
    for (int b = 0; b < NB; ++b) s += acc[b];
    sink[((size_t)blockIdx.y * gridDim.x + blockIdx.x) * 256 + tid] = s;
}

// Distinct names -> distinguishable rows in the counter table.
__launch_bounds__(256, 4) __global__
void probe_full(const float* x, const float4* pk2, float* sink)
{ probe_body<0, 0, 0, 0>(x, pk2, sink); }

__launch_bounds__(256, 4) __global__
void probe_nolog(const float* x, const float4* pk2, float* sink)
{ probe_body<1, 0, 0, 0>(x, pk2, sink); }

__launch_bounds__(256, 4) __global__
void probe_nolds(const float* x, const float4* pk2, float* sink)
{ probe_body<0, 1, 0, 0>(x, pk2, sink); }

__launch_bounds__(256, 4) __global__
void probe_novmem(const float* x, const float4* pk2, float* sink)
{ probe_body<0, 0, 1, 0>(x, pk2, sink); }

__launch_bounds__(256, 4) __global__
void probe_skel(const float* x, const float4* pk2, float* sink)
{ probe_body<0, 0, 0, 1>(x, pk2, sink); }

// Fallback (workspace too small): direct stabilized LSE.
__global__ void tropical_fallback(const float* __restrict__ x,
                                  const float* __restrict__ wp,
                                  const float* __restrict__ wq,
                                  float* __restrict__ out) {
    const int o = blockIdx.x * 16 + (threadIdx.x & 15);
    const int b = blockIdx.y * 16 + (threadIdx.x >> 4);
    float acc = 0.f;
    for (int i = 0; i < IN_DIM; ++i) {
        const float xv = x[b * IN_DIM + i];
        const float* p = wp + (size_t)(i * OUT_DIM + o) * NDEG;
        const float* q = wq + (size_t)(i * OUT_DIM + o) * NDEG;
        float lp[NDEG], lq[NDEG], mP = -1e30f, mQ = -1e30f;
#pragma unroll
        for (int d = 0; d < NDEG; ++d) {
            lp[d] = xv * d + p[d]; mP = fmaxf(mP, lp[d]);
            lq[d] = xv * d + q[d]; mQ = fmaxf(mQ, lq[d]);
        }
        float sP = 0.f, sQ = 0.f;
#pragma unroll
        for (int d = 0; d < NDEG; ++d) {
            sP += __expf(lp[d] - mP);
            sQ += __expf(lq[d] - mQ);
        }
        acc += (mP + __logf(sP)) - (mQ + __logf(sQ));
    }
    out[b * OUT_DIM + o] = acc;
}

extern "C" void kernel_launch(void* const* d_in, const int* in_sizes, int n_in,
                              void* d_out, int out_size, void* d_ws, size_t ws_size,
                              hipStream_t stream) {
    const float* x  = (const float*)d_in[0];
    const float* wp = (const float*)d_in[2];
    const float* wq = (const float*)d_in[3];
    float* out = (float*)d_out;

    const size_t pk_bytes   = (size_t)IN_DIM * OUT_DIM * 12 * sizeof(float);  // 3 MiB
    const size_t sink_bytes = (size_t)2048 * 256 * sizeof(float);             // 2 MiB

    if (ws_size >= pk_bytes) {
        float4* pk2 = (float4*)d_ws;
        float* sink = (ws_size >= pk_bytes + sink_bytes)
                          ? (float*)((char*)d_ws + pk_bytes)
                          : (float*)d_ws;   // overlap ok: prep rewrites pk2

        prep_pack<<<(IN_DIM * OUT_DIM + 255) / 256, 256, 0, stream>>>(wp, wq, pk2);

        dim3 grid(OUT_DIM / OT, BATCH / NB);   // 32 x 64 = 2048 blocks
        tropical_main<<<grid, 256, 0, stream>>>(x, (const float4*)pk2, out);

        // ---- R12 diagnostic probes (distinct names -> top-5 rows) ----
        probe_full  <<<grid, 256, 0, stream>>>(x, (const float4*)pk2, sink);
        probe_nolog <<<grid, 256, 0, stream>>>(x, (const float4*)pk2, sink);
        probe_nolds <<<grid, 256, 0, stream>>>(x, (const float4*)pk2, sink);
        probe_novmem<<<grid, 256, 0, stream>>>(x, (const float4*)pk2, sink);
        probe_skel  <<<grid, 256, 0, stream>>>(x, (const float4*)pk2, sink);
    } else {
        dim3 grid(OUT_DIM / 16, BATCH / 16);
        tropical_fallback<<<grid, 256, 0, stream>>>(x, wp, wq, out);
    }
}

// Round 13
// 23.135 us; speedup vs baseline: 24.1190x; 24.1190x over previous
//
#include <hip/hip_runtime.h>
#include <math.h>

#define BATCH   512
#define IN_DIM  256
#define OUT_DIM 256
#define NDEG    6     // degree+1

// Geometry (R6/R7/R10-proven): 256 threads = 8 o-lanes x 32 i-segments; NB=8
// b-accumulators; lane-ordered coef layout; 2^-18 prescale (4-i log batch);
// op_sel packed Horner.  R13: fused prep (pk2 + texp) with XCD-affine
// mapping (prep block p%8 == o_blk%8 == main-block XCD), copy-only staging
// in main, two-stage parallel reduce.
#define OT     8     // o per block
#define NSEG   32    // i-segments per block (tid>>3)
#define ISEG   8     // i's per segment
#define NB     8     // b per block (register accumulators)

typedef float v2f __attribute__((ext_vector_type(2)));

// NOTE (R12 finding): v_pk_fma_f32 has NO throughput edge on CDNA4 (FP32
// peak 157.3 TF == scalar FMA rate; pk executes in 2 passes). We keep it
// only for instruction-count compression.
__device__ __forceinline__ v2f pk_fma_blo(v2f a, v2f t, v2f c) {
    v2f d;
    asm("v_pk_fma_f32 %0, %1, %2, %3 op_sel:[0,0,0] op_sel_hi:[1,0,1]"
        : "=v"(d) : "v"(a), "v"(t), "v"(c));
    return d;
}
__device__ __forceinline__ v2f pk_fma_bhi(v2f a, v2f t, v2f c) {
    v2f d;
    asm("v_pk_fma_f32 %0, %1, %2, %3 op_sel:[0,1,0] op_sel_hi:[1,1,1]"
        : "=v"(d) : "v"(a), "v"(t), "v"(c));
    return d;
}
__device__ __forceinline__ v2f pk_mul(v2f a, v2f b) {
    v2f d;
    asm("v_pk_mul_f32 %0, %1, %2" : "=v"(d) : "v"(a), "v"(b));
    return d;
}

#define PRESCALE 12.476649250079015f   // 18 * ln2

// Fused prep: blocks [0,256) fill pk2 (XCD-affine: block p handles
// o_blk = p%32, i-chunk = p/32, so p%8 == o_blk%8 == reader XCD);
// blocks [256,384) fill texp = exp(x) as float4.
__global__ void prep_fused(const float* __restrict__ x,
                           const float* __restrict__ wp,
                           const float* __restrict__ wq,
                           float4* __restrict__ pk2,
                           float4* __restrict__ texp4) {
    const int p   = blockIdx.x;
    const int tid = threadIdx.x;
    if (p < 256) {
        const int ob  = p & 31;            // o_blk (matches reader XCD via %8)
        const int ch  = p >> 5;            // i-chunk 0..7
        const int i   = ch * 32 + (tid >> 3);
        const int o_l = tid & 7;
        const int o   = ob * 8 + o_l;
        const int j   = i * OUT_DIM + o;

        const int seg_blk = i >> 6;
        const int seg     = (i >> 3) & 7;
        const int ii      = i & 7;
        const size_t base =
            ((size_t)(ob * 4 + seg_blk) * 24) * 64 + seg * 8 + o_l;

        const float2* wp2 = (const float2*)wp;
        const float2* wq2 = (const float2*)wq;
        float2 p0 = wp2[j * 3], p1 = wp2[j * 3 + 1], p2 = wp2[j * 3 + 2];
        float2 q0 = wq2[j * 3], q1 = wq2[j * 3 + 1], q2 = wq2[j * 3 + 2];
        pk2[base + (ii * 3 + 0) * 64] =
            make_float4(__expf(p0.x - PRESCALE), __expf(q0.x - PRESCALE),
                        __expf(p0.y - PRESCALE), __expf(q0.y - PRESCALE));
        pk2[base + (ii * 3 + 1) * 64] =
            make_float4(__expf(p1.x - PRESCALE), __expf(q1.x - PRESCALE),
                        __expf(p1.y - PRESCALE), __expf(q1.y - PRESCALE));
        pk2[base + (ii * 3 + 2) * 64] =
            make_float4(__expf(p2.x - PRESCALE), __expf(q2.x - PRESCALE),
                        __expf(p2.y - PRESCALE), __expf(q2.y - PRESCALE));
    } else {
        // texp: 131072 floats = 32768 float4; 128 blocks x 256 threads x 1
        const int idx = (p - 256) * 256 + tid;
        const float4 v = ((const float4*)x)[idx];
        texp4[idx] = make_float4(__expf(v.x), __expf(v.y),
                                 __expf(v.z), __expf(v.w));
    }
}

// Packed Horner, t broadcast via op_sel from a (t0,t1) register pair.
__device__ __forceinline__ v2f horner_lo(float4 c0, float4 c1, float4 c2, v2f tp) {
    const v2f C0 = {c0.x, c0.y}, C1 = {c0.z, c0.w};
    const v2f C2 = {c1.x, c1.y}, C3 = {c1.z, c1.w};
    const v2f C4 = {c2.x, c2.y}, C5 = {c2.z, c2.w};
    v2f r = pk_fma_blo(C5, tp, C4);
    r = pk_fma_blo(r, tp, C3);
    r = pk_fma_blo(r, tp, C2);
    r = pk_fma_blo(r, tp, C1);
    r = pk_fma_blo(r, tp, C0);
    return r;
}
__device__ __forceinline__ v2f horner_hi(float4 c0, float4 c1, float4 c2, v2f tp) {
    const v2f C0 = {c0.x, c0.y}, C1 = {c0.z, c0.w};
    const v2f C2 = {c1.x, c1.y}, C3 = {c1.z, c1.w};
    const v2f C4 = {c2.x, c2.y}, C5 = {c2.z, c2.w};
    v2f r = pk_fma_bhi(C5, tp, C4);
    r = pk_fma_bhi(r, tp, C3);
    r = pk_fma_bhi(r, tp, C2);
    r = pk_fma_bhi(r, tp, C1);
    r = pk_fma_bhi(r, tp, C0);
    return r;
}

// Grid = (OUT_DIM/OT = 32, BATCH/NB = 64) = 2048 blocks = 8/CU.
// Linear id%8 = o_blk%8 -> all readers of a coef slab are on one XCD.
__launch_bounds__(256, 4)
__global__ void tropical_main(const float4* __restrict__ texp4,
                              const float4* __restrict__ pk2,
                              float* __restrict__ out) {
    // Phase A: t[b][i], 8 b x 256 i (2048 f). Phase B: slab reduce
    // (NSEG slabs, stride 65 = 2080 f) + 256 partials. Shared allocation.
    __shared__ float lds[NSEG * (NB * OT + 1) + 256];   // 2336 floats

    const int tid = threadIdx.x;
    const int o_l = tid & (OT - 1);
    const int b0  = blockIdx.y * NB;

    // ---- stage t: pure copy from texp (8 floats / thread) ----
    {
        const int r = tid >> 5;            // 0..7
        const int c = (tid & 31) * 8;      // 0..248
        const float4* tx = texp4 + ((size_t)(b0 + r) * IN_DIM + c) / 4;
        const float4 v0 = tx[0];
        const float4 v1 = tx[1];
        *(float4*)&lds[r * IN_DIM + c]     = v0;
        *(float4*)&lds[r * IN_DIM + c + 4] = v1;
    }
    __syncthreads();

    float acc[NB];
#pragma unroll
    for (int b = 0; b < NB; ++b) acc[b] = 0.f;

    const int lane = tid & 63;
    const int wv   = tid >> 6;
    const float4* __restrict__ cb =
        pk2 + ((size_t)(blockIdx.x * 4 + wv) * 24) * 64 + lane;

    const int i0 = (tid >> 3) * ISEG;
    const float* __restrict__ tb = lds + i0;

#pragma unroll
    for (int g = 0; g < 2; ++g) {
        float4 C[12];
#pragma unroll
        for (int k = 0; k < 12; ++k)
            C[k] = cb[(g * 12 + k) * 64];

#pragma unroll
        for (int b = 0; b < NB; ++b) {
            const float4 tv = *(const float4*)(tb + b * IN_DIM + g * 4);
            const v2f txy = {tv.x, tv.y};
            const v2f tzw = {tv.z, tv.w};
            const v2f PQ0 = horner_lo(C[0], C[1],  C[2],  txy);
            const v2f PQ1 = horner_hi(C[3], C[4],  C[5],  txy);
            const v2f PQ2 = horner_lo(C[6], C[7],  C[8],  tzw);
            const v2f PQ3 = horner_hi(C[9], C[10], C[11], tzw);
            const v2f m = pk_mul(pk_mul(PQ0, PQ1), pk_mul(PQ2, PQ3));
            acc[b] += __log2f(m.x) - __log2f(m.y);
        }
    }

    __syncthreads();   // done with t; reuse LDS as reduce buffer
    const int seg = tid >> 3;
#pragma unroll
    for (int b = 0; b < NB; ++b)
        lds[seg * (NB * OT + 1) + b * OT + o_l] = acc[b];
    __syncthreads();

    // ---- two-stage parallel reduce over 32 slabs ----
    {
        const int outI = tid >> 2;         // 0..63  (br*8 + orr)
        const int quad = tid & 3;          // 0..3
        const int br   = outI >> 3;
        const int orr  = outI & 7;
        float s = 0.f;
#pragma unroll
        for (int g2 = 0; g2 < 8; ++g2)
            s += lds[(quad * 8 + g2) * (NB * OT + 1) + br * OT + orr];
        lds[NSEG * (NB * OT + 1) + outI * 4 + quad] = s;
    }
    __syncthreads();

    if (tid < NB * OT) {                   // 64 outputs
        const float* pr = lds + NSEG * (NB * OT + 1) + tid * 4;
        const float s = (pr[0] + pr[1]) + (pr[2] + pr[3]);
        const int br = tid >> 3, orr = tid & 7;
        out[(size_t)(b0 + br) * OUT_DIM + blockIdx.x * OT + orr] =
            s * 0.6931471805599453f;   // * ln2
    }
}

// Fallback (workspace too small): direct stabilized LSE.
__global__ void tropical_fallback(const float* __restrict__ x,
                                  const float* __restrict__ wp,
                                  const float* __restrict__ wq,
                                  float* __restrict__ out) {
    const int o = blockIdx.x * 16 + (threadIdx.x & 15);
    const int b = blockIdx.y * 16 + (threadIdx.x >> 4);
    float acc = 0.f;
    for (int i = 0; i < IN_DIM; ++i) {
        const float xv = x[b * IN_DIM + i];
        const float* p = wp + (size_t)(i * OUT_DIM + o) * NDEG;
        const float* q = wq + (size_t)(i * OUT_DIM + o) * NDEG;
        float lp[NDEG], lq[NDEG], mP = -1e30f, mQ = -1e30f;
#pragma unroll
        for (int d = 0; d < NDEG; ++d) {
            lp[d] = xv * d + p[d]; mP = fmaxf(mP, lp[d]);
            lq[d] = xv * d + q[d]; mQ = fmaxf(mQ, lq[d]);
        }
        float sP = 0.f, sQ = 0.f;
#pragma unroll
        for (int d = 0; d < NDEG; ++d) {
            sP += __expf(lp[d] - mP);
            sQ += __expf(lq[d] - mQ);
        }
        acc += (mP + __logf(sP)) - (mQ + __logf(sQ));
    }
    out[b * OUT_DIM + o] = acc;
}

extern "C" void kernel_launch(void* const* d_in, const int* in_sizes, int n_in,
                              void* d_out, int out_size, void* d_ws, size_t ws_size,
                              hipStream_t stream) {
    const float* x  = (const float*)d_in[0];
    // d_in[1] = slopes (arange(6)) — implicit in the polynomial powers.
    const float* wp = (const float*)d_in[2];
    const float* wq = (const float*)d_in[3];
    float* out = (float*)d_out;

    const size_t pk_bytes   = (size_t)IN_DIM * OUT_DIM * 12 * sizeof(float);  // 3 MiB
    const size_t texp_bytes = (size_t)BATCH * IN_DIM * sizeof(float);         // 0.5 MiB

    if (ws_size >= pk_bytes + texp_bytes) {
        float4* pk2   = (float4*)d_ws;
        float4* texp4 = (float4*)((char*)d_ws + pk_bytes);

        prep_fused<<<384, 256, 0, stream>>>(x, wp, wq, pk2, texp4);

        dim3 grid(OUT_DIM / OT, BATCH / NB);   // 32 x 64 = 2048 blocks
        tropical_main<<<grid, 256, 0, stream>>>(texp4, (const float4*)pk2, out);
    } else {
        dim3 grid(OUT_DIM / 16, BATCH / 16);
        tropical_fallback<<<grid, 256, 0, stream>>>(x, wp, wq, out);
    }
}

// Round 14
// 22.228 us; speedup vs baseline: 25.1029x; 1.0408x over previous
//
#include <hip/hip_runtime.h>
#include <math.h>

#define BATCH   512
#define IN_DIM  256
#define OUT_DIM 256

// Geometry (R6/R7/R10-proven): 256 threads = 8 o-lanes x 32 i-segments;
// NB=8 b-accumulators; 2^-18 prescale (4-i log batching); op_sel packed
// Horner.  R14: SINGLE-DISPATCH FUSION -- each thread computes its own 24
// coefficient float4s in-register (exp on the ~idle trans pipe, hidden
// under the VALU-bound inner loop) straight from wp/wq. No prep kernel,
// no workspace, no pk2/texp round-trips.
#define OT     8     // o per block
#define NSEG   32    // i-segments per block (tid>>3)
#define ISEG   8     // i's per segment
#define NB     8     // b per block (register accumulators)

typedef float v2f __attribute__((ext_vector_type(2)));

// NOTE (R12 finding): v_pk_fma_f32 has NO throughput edge on CDNA4 (FP32
// 157.3 TF vector peak == scalar FMA rate; pk executes over 2 passes).
// Kept for instruction-count compression + op_sel broadcast only.
__device__ __forceinline__ v2f pk_fma_blo(v2f a, v2f t, v2f c) {
    v2f d;
    asm("v_pk_fma_f32 %0, %1, %2, %3 op_sel:[0,0,0] op_sel_hi:[1,0,1]"
        : "=v"(d) : "v"(a), "v"(t), "v"(c));
    return d;
}
__device__ __forceinline__ v2f pk_fma_bhi(v2f a, v2f t, v2f c) {
    v2f d;
    asm("v_pk_fma_f32 %0, %1, %2, %3 op_sel:[0,1,0] op_sel_hi:[1,1,1]"
        : "=v"(d) : "v"(a), "v"(t), "v"(c));
    return d;
}
__device__ __forceinline__ v2f pk_mul(v2f a, v2f b) {
    v2f d;
    asm("v_pk_mul_f32 %0, %1, %2" : "=v"(d) : "v"(a), "v"(b));
    return d;
}

#define PRESCALE 12.476649250079015f   // 18 * ln2

// Packed Horner, t broadcast via op_sel from a (t0,t1) register pair.
__device__ __forceinline__ v2f horner_lo(float4 c0, float4 c1, float4 c2, v2f tp) {
    const v2f C0 = {c0.x, c0.y}, C1 = {c0.z, c0.w};
    const v2f C2 = {c1.x, c1.y}, C3 = {c1.z, c1.w};
    const v2f C4 = {c2.x, c2.y}, C5 = {c2.z, c2.w};
    v2f r = pk_fma_blo(C5, tp, C4);
    r = pk_fma_blo(r, tp, C3);
    r = pk_fma_blo(r, tp, C2);
    r = pk_fma_blo(r, tp, C1);
    r = pk_fma_blo(r, tp, C0);
    return r;
}
__device__ __forceinline__ v2f horner_hi(float4 c0, float4 c1, float4 c2, v2f tp) {
    const v2f C0 = {c0.x, c0.y}, C1 = {c0.z, c0.w};
    const v2f C2 = {c1.x, c1.y}, C3 = {c1.z, c1.w};
    const v2f C4 = {c2.x, c2.y}, C5 = {c2.z, c2.w};
    v2f r = pk_fma_bhi(C5, tp, C4);
    r = pk_fma_bhi(r, tp, C3);
    r = pk_fma_bhi(r, tp, C2);
    r = pk_fma_bhi(r, tp, C1);
    r = pk_fma_bhi(r, tp, C0);
    return r;
}

// Grid = (OUT_DIM/OT = 32, BATCH/NB = 64) = 2048 blocks. One dispatch total.
__launch_bounds__(256, 4)
__global__ void tropical_fused(const float* __restrict__ x,
                               const float* __restrict__ wp,
                               const float* __restrict__ wq,
                               float* __restrict__ out) {
    // Phase A: t[b][i], 8 b x 256 i (2048 f). Phase B: slab reduce
    // (32 slabs, stride 65) + 256 stage-2 partials.
    __shared__ float lds[NSEG * (NB * OT + 1) + 256];   // 2336 floats

    const int tid = threadIdx.x;
    const int o_l = tid & (OT - 1);
    const int b0  = blockIdx.y * NB;

    // ---- stage t = exp(x): 8 b-rows x 256 i (8 floats / thread) ----
    {
        const int r = tid >> 5;            // 0..7
        const int c = (tid & 31) * 8;      // 0..248
        const float* xr = x + (size_t)(b0 + r) * IN_DIM + c;
        const float4 v0 = *(const float4*)(xr);
        const float4 v1 = *(const float4*)(xr + 4);
        float4 w0, w1;
        w0.x = __expf(v0.x); w0.y = __expf(v0.y);
        w0.z = __expf(v0.z); w0.w = __expf(v0.w);
        w1.x = __expf(v1.x); w1.y = __expf(v1.y);
        w1.z = __expf(v1.z); w1.w = __expf(v1.w);
        *(float4*)&lds[r * IN_DIM + c]     = w0;
        *(float4*)&lds[r * IN_DIM + c + 4] = w1;
    }
    __syncthreads();

    float acc[NB];
#pragma unroll
    for (int b = 0; b < NB; ++b) acc[b] = 0.f;

    const int seg    = tid >> 3;           // 0..31
    const int i_base = seg * ISEG;
    const int o      = blockIdx.x * OT + o_l;
    const float* __restrict__ tb = lds + i_base;

#pragma unroll
    for (int g = 0; g < 2; ++g) {          // 2 groups of 4 i's
        // ---- in-register coefficient build: exp(w - 18ln2), trans pipe ----
        // C[ii*3+w] = (p_{2w}, q_{2w}, p_{2w+1}, q_{2w+1}) for i = i_base+g*4+ii
        float4 C[12];
#pragma unroll
        for (int ii = 0; ii < 4; ++ii) {
            const int j = (i_base + g * 4 + ii) * OUT_DIM + o;
            const float2* P2 = (const float2*)wp + (size_t)j * 3;
            const float2* Q2 = (const float2*)wq + (size_t)j * 3;
            const float2 p0 = P2[0], p1 = P2[1], p2 = P2[2];
            const float2 q0 = Q2[0], q1 = Q2[1], q2 = Q2[2];
            C[ii * 3 + 0] = make_float4(
                __expf(p0.x - PRESCALE), __expf(q0.x - PRESCALE),
                __expf(p0.y - PRESCALE), __expf(q0.y - PRESCALE));
            C[ii * 3 + 1] = make_float4(
                __expf(p1.x - PRESCALE), __expf(q1.x - PRESCALE),
                __expf(p1.y - PRESCALE), __expf(q1.y - PRESCALE));
            C[ii * 3 + 2] = make_float4(
                __expf(p2.x - PRESCALE), __expf(q2.x - PRESCALE),
                __expf(p2.y - PRESCALE), __expf(q2.y - PRESCALE));
        }

        // ---- VALU-bound inner loop (unchanged from R10) ----
#pragma unroll
        for (int b = 0; b < NB; ++b) {
            const float4 tv = *(const float4*)(tb + b * IN_DIM + g * 4);
            const v2f txy = {tv.x, tv.y};
            const v2f tzw = {tv.z, tv.w};
            const v2f PQ0 = horner_lo(C[0], C[1],  C[2],  txy);
            const v2f PQ1 = horner_hi(C[3], C[4],  C[5],  txy);
            const v2f PQ2 = horner_lo(C[6], C[7],  C[8],  tzw);
            const v2f PQ3 = horner_hi(C[9], C[10], C[11], tzw);
            const v2f m = pk_mul(pk_mul(PQ0, PQ1), pk_mul(PQ2, PQ3));
            acc[b] += __log2f(m.x) - __log2f(m.y);
        }
    }

    __syncthreads();   // done with t; reuse LDS as reduce buffer
#pragma unroll
    for (int b = 0; b < NB; ++b)
        lds[seg * (NB * OT + 1) + b * OT + o_l] = acc[b];
    __syncthreads();

    // ---- two-stage parallel reduce over 32 slabs ----
    {
        const int outI = tid >> 2;         // 0..63  (br*8 + orr)
        const int quad = tid & 3;          // 0..3
        const int br   = outI >> 3;
        const int orr  = outI & 7;
        float s = 0.f;
#pragma unroll
        for (int g2 = 0; g2 < 8; ++g2)
            s += lds[(quad * 8 + g2) * (NB * OT + 1) + br * OT + orr];
        lds[NSEG * (NB * OT + 1) + outI * 4 + quad] = s;
    }
    __syncthreads();

    if (tid < NB * OT) {                   // 64 outputs
        const float* pr = lds + NSEG * (NB * OT + 1) + tid * 4;
        const float s = (pr[0] + pr[1]) + (pr[2] + pr[3]);
        const int br = tid >> 3, orr = tid & 7;
        out[(size_t)(b0 + br) * OUT_DIM + blockIdx.x * OT + orr] =
            s * 0.6931471805599453f;   // * ln2
    }
}

extern "C" void kernel_launch(void* const* d_in, const int* in_sizes, int n_in,
                              void* d_out, int out_size, void* d_ws, size_t ws_size,
                              hipStream_t stream) {
    const float* x  = (const float*)d_in[0];
    // d_in[1] = slopes (arange(6)) — implicit in the polynomial powers.
    const float* wp = (const float*)d_in[2];
    const float* wq = (const float*)d_in[3];
    float* out = (float*)d_out;

    dim3 grid(OUT_DIM / OT, BATCH / NB);   // 32 x 64 = 2048 blocks
    tropical_fused<<<grid, 256, 0, stream>>>(x, wp, wq, out);
}

// Round 15
// 20.085 us; speedup vs baseline: 27.7821x; 1.1067x over previous
//
#include <hip/hip_runtime.h>
#include <math.h>

#define BATCH   512
#define IN_DIM  256
#define OUT_DIM 256

// R15: fused single-dispatch (R14) with NB=16 -- halves the coefficient-exp
// and x-staging redundancy (BATCH/NB: 64 -> 32 blocks share each (i,o) coef).
// Unlike R11's failed NB=16: only ONE C[12] live at a time (no prefetch
// pair), so acc16+C48+transients ~= 105 VGPR fits the 128 cap at 4 waves/EU.
// Inner loop (VALU-bound per R12 probes) unchanged per unit work.
#define OT     8     // o per block
#define NSEG   32    // i-segments per block (tid>>3)
#define ISEG   8     // i's per segment
#define NB     16    // b per block (register accumulators)

typedef float v2f __attribute__((ext_vector_type(2)));

// NOTE (R12 finding): v_pk_fma_f32 has NO throughput edge on CDNA4 (157.3 TF
// vector peak == scalar FMA rate; pk executes over 2 passes). Kept for
// instruction-count compression + op_sel broadcast of t.
__device__ __forceinline__ v2f pk_fma_blo(v2f a, v2f t, v2f c) {
    v2f d;
    asm("v_pk_fma_f32 %0, %1, %2, %3 op_sel:[0,0,0] op_sel_hi:[1,0,1]"
        : "=v"(d) : "v"(a), "v"(t), "v"(c));
    return d;
}
__device__ __forceinline__ v2f pk_fma_bhi(v2f a, v2f t, v2f c) {
    v2f d;
    asm("v_pk_fma_f32 %0, %1, %2, %3 op_sel:[0,1,0] op_sel_hi:[1,1,1]"
        : "=v"(d) : "v"(a), "v"(t), "v"(c));
    return d;
}
__device__ __forceinline__ v2f pk_mul(v2f a, v2f b) {
    v2f d;
    asm("v_pk_mul_f32 %0, %1, %2" : "=v"(d) : "v"(a), "v"(b));
    return d;
}

#define PRESCALE 12.476649250079015f   // 18 * ln2

// Packed Horner, t broadcast via op_sel from a (t0,t1) register pair.
__device__ __forceinline__ v2f horner_lo(float4 c0, float4 c1, float4 c2, v2f tp) {
    const v2f C0 = {c0.x, c0.y}, C1 = {c0.z, c0.w};
    const v2f C2 = {c1.x, c1.y}, C3 = {c1.z, c1.w};
    const v2f C4 = {c2.x, c2.y}, C5 = {c2.z, c2.w};
    v2f r = pk_fma_blo(C5, tp, C4);
    r = pk_fma_blo(r, tp, C3);
    r = pk_fma_blo(r, tp, C2);
    r = pk_fma_blo(r, tp, C1);
    r = pk_fma_blo(r, tp, C0);
    return r;
}
__device__ __forceinline__ v2f horner_hi(float4 c0, float4 c1, float4 c2, v2f tp) {
    const v2f C0 = {c0.x, c0.y}, C1 = {c0.z, c0.w};
    const v2f C2 = {c1.x, c1.y}, C3 = {c1.z, c1.w};
    const v2f C4 = {c2.x, c2.y}, C5 = {c2.z, c2.w};
    v2f r = pk_fma_bhi(C5, tp, C4);
    r = pk_fma_bhi(r, tp, C3);
    r = pk_fma_bhi(r, tp, C2);
    r = pk_fma_bhi(r, tp, C1);
    r = pk_fma_bhi(r, tp, C0);
    return r;
}

// Grid = (OUT_DIM/OT = 32, BATCH/NB = 32) = 1024 blocks = 4/CU. One dispatch.
__launch_bounds__(256, 4)
__global__ void tropical_fused(const float* __restrict__ x,
                               const float* __restrict__ wp,
                               const float* __restrict__ wq,
                               float* __restrict__ out) {
    // Phase A: t[b][i], 16 b x 256 i (4096 f). Phase B: slab reduce
    // (32 slabs, stride NB*OT+1 = 129 -> 4128 f). Shared allocation.
    __shared__ float lds[NSEG * (NB * OT + 1)];   // 4128 floats = 16.5 KiB

    const int tid = threadIdx.x;
    const int o_l = tid & (OT - 1);
    const int b0  = blockIdx.y * NB;

    // ---- stage t = exp(x): 16 b-rows x 256 i (16 floats / thread) ----
    {
        const int r = tid >> 4;            // 0..15
        const int c = (tid & 15) * 16;     // 0..240
        const float* xr = x + (size_t)(b0 + r) * IN_DIM + c;
#pragma unroll
        for (int q = 0; q < 4; ++q) {
            const float4 v = *(const float4*)(xr + q * 4);
            float4 w;
            w.x = __expf(v.x); w.y = __expf(v.y);
            w.z = __expf(v.z); w.w = __expf(v.w);
            *(float4*)&lds[r * IN_DIM + c + q * 4] = w;
        }
    }
    __syncthreads();

    float acc[NB];
#pragma unroll
    for (int b = 0; b < NB; ++b) acc[b] = 0.f;

    const int seg    = tid >> 3;           // 0..31
    const int i_base = seg * ISEG;
    const int o      = blockIdx.x * OT + o_l;
    const float* __restrict__ tb = lds + i_base;

#pragma unroll
    for (int g = 0; g < 2; ++g) {          // 2 groups of 4 i's
        // ---- in-register coefficient build: exp(w - 18ln2) ----
        float4 C[12];
#pragma unroll
        for (int ii = 0; ii < 4; ++ii) {
            const int j = (i_base + g * 4 + ii) * OUT_DIM + o;
            const float2* P2 = (const float2*)wp + (size_t)j * 3;
            const float2* Q2 = (const float2*)wq + (size_t)j * 3;
            const float2 p0 = P2[0], p1 = P2[1], p2 = P2[2];
            const float2 q0 = Q2[0], q1 = Q2[1], q2 = Q2[2];
            C[ii * 3 + 0] = make_float4(
                __expf(p0.x - PRESCALE), __expf(q0.x - PRESCALE),
                __expf(p0.y - PRESCALE), __expf(q0.y - PRESCALE));
            C[ii * 3 + 1] = make_float4(
                __expf(p1.x - PRESCALE), __expf(q1.x - PRESCALE),
                __expf(p1.y - PRESCALE), __expf(q1.y - PRESCALE));
            C[ii * 3 + 2] = make_float4(
                __expf(p2.x - PRESCALE), __expf(q2.x - PRESCALE),
                __expf(p2.y - PRESCALE), __expf(q2.y - PRESCALE));
        }

        // ---- VALU-bound inner loop (R10 body, NB=16) ----
#pragma unroll
        for (int b = 0; b < NB; ++b) {
            const float4 tv = *(const float4*)(tb + b * IN_DIM + g * 4);
            const v2f txy = {tv.x, tv.y};
            const v2f tzw = {tv.z, tv.w};
            const v2f PQ0 = horner_lo(C[0], C[1],  C[2],  txy);
            const v2f PQ1 = horner_hi(C[3], C[4],  C[5],  txy);
            const v2f PQ2 = horner_lo(C[6], C[7],  C[8],  tzw);
            const v2f PQ3 = horner_hi(C[9], C[10], C[11], tzw);
            const v2f m = pk_mul(pk_mul(PQ0, PQ1), pk_mul(PQ2, PQ3));
            acc[b] += __log2f(m.x) - __log2f(m.y);
        }
    }

    __syncthreads();   // done with t; reuse LDS as reduce buffer
#pragma unroll
    for (int b = 0; b < NB; ++b)
        lds[seg * (NB * OT + 1) + b * OT + o_l] = acc[b];
    __syncthreads();

    if (tid < NB * OT) {                   // 128 outputs
        const int br = tid >> 3, orr = tid & (OT - 1);
        float s = 0.f;
#pragma unroll
        for (int g2 = 0; g2 < NSEG; ++g2)
            s += lds[g2 * (NB * OT + 1) + br * OT + orr];
        out[(size_t)(b0 + br) * OUT_DIM + blockIdx.x * OT + orr] =
            s * 0.6931471805599453f;   // * ln2
    }
}

extern "C" void kernel_launch(void* const* d_in, const int* in_sizes, int n_in,
                              void* d_out, int out_size, void* d_ws, size_t ws_size,
                              hipStream_t stream) {
    const float* x  = (const float*)d_in[0];
    // d_in[1] = slopes (arange(6)) — implicit in the polynomial powers.
    const float* wp = (const float*)d_in[2];
    const float* wq = (const float*)d_in[3];
    float* out = (float*)d_out;

    dim3 grid(OUT_DIM / OT, BATCH / NB);   // 32 x 32 = 1024 blocks
    tropical_fused<<<grid, 256, 0, stream>>>(x, wp, wq, out);
}